// Round 11
// baseline (847.076 us; speedup 1.0000x reference)
//
#include <hip/hip_runtime.h>

// PointPillarScatter3d — R11 ABLATION ROUND (visible this time).
// Each ablation repeats internally (x4/x8) so its dispatch clears the ~160us
// top-5 visibility bar set by the harness's poison fills. Real gather (R9,
// unchanged) runs LAST and overwrites the full output -> correctness intact.
// Headline dur_us deliberately regresses this round; data is the payload.

typedef float nfloat4 __attribute__((ext_vector_type(4)));

constexpr int NXc = 360;
constexpr int NYc = 360;
constexpr int NZc = 1;
constexpr int Cc  = 128;
constexpr int Bc  = 4;
constexpr int Sc  = NZc * NYc * NXc;   // 129600
constexpr int BSc = Bc * Sc;           // 518400

constexpr int TSC   = 540;
constexpr int NST   = BSc / TSC;       // 960
constexpr int CHG   = 16;
constexpr int NCG   = Cc / CHG;        // 8
constexpr int CAP3  = 240;
constexpr int LSTR  = TSC + 1;
constexpr int CSTRIDE = 16;

constexpr int REP_W = 4;               // write-ablation repeats
constexpr int REP_R = 8;               // read-ablation repeats

// ---- fill: bin points into 540-cell s-tiles (R9, unchanged) -----------------
__global__ void pps_fill3(const int* __restrict__ coords,
                          int* __restrict__ cnt, int* __restrict__ list, int N) {
    int i = blockIdx.x * blockDim.x + threadIdx.x;
    if (i >= N) return;
    int4 c = reinterpret_cast<const int4*>(coords)[i];
    int g = c.x * Sc + c.y * (NYc * NXc) + c.z * NXc + c.w;
    int st = g / TSC;
    int cell = g - st * TSC;
    int slot = atomicAdd(&cnt[st * CSTRIDE], 1);
    if (slot < CAP3) list[st * CAP3 + slot] = (i << 10) | cell;
}

// ---- ABL A: linear NT writes of full output, x4 ------------------------------
__global__ __launch_bounds__(256)
void abl_write_linear(float* __restrict__ out, int n4) {
    nfloat4 z = (nfloat4)0.0f;
    for (int r = 0; r < REP_W; ++r)
        for (int i = blockIdx.x * blockDim.x + threadIdx.x; i < n4;
             i += gridDim.x * blockDim.x)
            __builtin_nontemporal_store(z, reinterpret_cast<nfloat4*>(out) + i);
}

// ---- ABL B: exact R9 strided write pattern (NT scalar), x4 -------------------
__global__ __launch_bounds__(512)
void abl_write_strided(float* __restrict__ out) {
    const int st = blockIdx.x % NST;
    const int cg = blockIdx.x / NST;
    const int t  = threadIdx.x;
    const int b  = st / (Sc / TSC);
    const int s0 = (st % (Sc / TSC)) * TSC;
    float* ob = out + ((size_t)b * Cc + cg * CHG) * Sc + s0;
    for (int r = 0; r < REP_W; ++r) {
        #pragma unroll
        for (int i = 0; i < 17; ++i) {
            int idx = i * 512 + t;
            if (idx < CHG * TSC) {
                int cl  = idx / TSC;
                int pos = idx - cl * TSC;
                __builtin_nontemporal_store(0.0f, ob + (size_t)cl * Sc + pos);
            }
        }
    }
}

// ---- ABL C: exact R9 scattered read pattern (volatile, asm-sunk), x8 ---------
__global__ __launch_bounds__(512)
void abl_read(const float* __restrict__ feat_,
              const int* __restrict__ tcnt,
              const int* __restrict__ list) {
    const volatile float* feat = feat_;    // force re-issue every rep
    __shared__ int slist[CAP3];
    __shared__ int sm_;
    const int st = blockIdx.x % NST;
    const int cg = blockIdx.x / NST;
    const int t  = threadIdx.x;
    if (t == 0) sm_ = min(tcnt[st * CSTRIDE], CAP3);
    if (t < CAP3) slist[t] = list[st * CAP3 + t];
    __syncthreads();
    const int w = t >> 6, l = t & 63, psub = l >> 4, ch = l & 15;
    const int m = sm_;
    for (int r = 0; r < REP_R; ++r) {
        for (int sb = w * 4; sb < m; sb += 32) {
            int slot = sb + psub;
            bool ok = slot < m;
            int e = slist[ok ? slot : 0];
            int p = e >> 10;
            if (ok) {
                float v = feat[(size_t)p * Cc + cg * CHG + ch];
                asm volatile("" :: "v"(v));   // keep load live, no store
            }
        }
    }
}

// ---- real gather (R9, unchanged; runs last, writes every output elem) -------
__global__ __launch_bounds__(512)
void pps_gather6(const float* __restrict__ feat,
                 const int* __restrict__ cnt,
                 const int* __restrict__ list,
                 float* __restrict__ out) {
    __shared__ __align__(16) float lsum[CHG * LSTR];
    __shared__ int   lcnt[TSC];
    __shared__ float linv[TSC];
    __shared__ int   slist[CAP3];
    __shared__ int   sm;

    const int st = blockIdx.x % NST;
    const int cg = blockIdx.x / NST;
    const int t  = threadIdx.x;

    for (int k = t; k < (CHG * LSTR) / 4; k += 512)
        reinterpret_cast<nfloat4*>(lsum)[k] = (nfloat4)0.0f;
    for (int k = t; k < TSC; k += 512) lcnt[k] = 0;
    if (t == 0) sm = min(cnt[st * CSTRIDE], CAP3);
    if (t < CAP3) slist[t] = list[st * CAP3 + t];
    __syncthreads();

    const int w = t >> 6, l = t & 63, psub = l >> 4, ch = l & 15;
    const int m = sm;
    #pragma unroll 2
    for (int sb = w * 4; sb < m; sb += 32) {
        int slot = sb + psub;
        bool ok = slot < m;
        int e = slist[ok ? slot : 0];
        int cell = e & 1023;
        int p = e >> 10;
        if (ok) {
            float v = feat[(size_t)p * Cc + cg * CHG + ch];
            atomicAdd(&lsum[ch * LSTR + cell], v);
            if (ch == 0) atomicAdd(&lcnt[cell], 1);
        }
    }
    __syncthreads();

    for (int k = t; k < TSC; k += 512) {
        int n = lcnt[k];
        linv[k] = n > 0 ? 1.0f / (float)n : 0.0f;
    }
    __syncthreads();

    const int b  = st / (Sc / TSC);
    const int s0 = (st % (Sc / TSC)) * TSC;
    float* ob = out + ((size_t)b * Cc + cg * CHG) * Sc + s0;
    #pragma unroll
    for (int i = 0; i < 17; ++i) {
        int idx = i * 512 + t;
        if (idx < CHG * TSC) {
            int cl  = idx / TSC;
            int pos = idx - cl * TSC;
            float val = lsum[cl * LSTR + pos] * linv[pos];
            __builtin_nontemporal_store(val, ob + (size_t)cl * Sc + pos);
        }
    }
}

// ---- launch -----------------------------------------------------------------
extern "C" void kernel_launch(void* const* d_in, const int* in_sizes, int n_in,
                              void* d_out, int out_size, void* d_ws, size_t ws_size,
                              hipStream_t stream) {
    const float* feat   = reinterpret_cast<const float*>(d_in[0]);
    const int*   coords = reinterpret_cast<const int*>(d_in[1]);
    float*       out    = reinterpret_cast<float*>(d_out);

    const int N = in_sizes[0] / Cc;  // 160000

    const size_t cnt_bytes  = (size_t)NST * CSTRIDE * sizeof(int);
    int* cnt  = reinterpret_cast<int*>(d_ws);
    int* list = reinterpret_cast<int*>((char*)d_ws + cnt_bytes);

    (void)hipMemsetAsync(d_ws, 0, cnt_bytes, stream);
    {
        int threads = 256;
        int blocks = (N + threads - 1) / threads;
        pps_fill3<<<blocks, threads, 0, stream>>>(coords, cnt, list, N);
    }

    // --- ablations (output-safe: gather6 overwrites everything afterward) ---
    abl_write_linear<<<2048, 256, 0, stream>>>(out, out_size / 4);       // NT linear x4
    abl_write_strided<<<NST * NCG, 512, 0, stream>>>(out);               // NT strided x4
    abl_read<<<NST * NCG, 512, 0, stream>>>(feat, cnt, list);            // scattered reads x8

    // --- real kernel (R9, unchanged) ---
    pps_gather6<<<NST * NCG, 512, 0, stream>>>(feat, cnt, list, out);
}